// Round 2
// baseline (320.874 us; speedup 1.0000x reference)
//
#include <hip/hip_runtime.h>
#include <math.h>

// Cone-beam forward projection (TIGRE Ax analogue).
// Volume: [B=2, NZ=96, NY=96, NX=96] f32, ZYX layout (x fastest).
// Output: [B=2, A=48, NV=96, NU=96] f32.
// One thread per ray; NS=96 samples.
//
// CORRECTNESS-CRITICAL: the reference integrand is DISCONTINUOUS at the
// cube faces (validity mask). We replicate the reference's f32 op sequence
// bit-for-bit on the position path: no fma contraction, per-sample
// src + d*t (no incremental march), IEEE sqrt + divide, correctly-rounded
// f32 trig via f64, jax-f32 linspace constant.

#define NZg 96
#define NYg 96
#define NXg 96
#define NVg 96
#define NUg 96
#define NAg 48
#define NSg 96
#define NBg 2

__global__ __launch_bounds__(256) void coneproj_kernel(
    const float* __restrict__ vol, float* __restrict__ out) {
#pragma clang fp contract(off)
    const int idx = blockIdx.x * blockDim.x + threadIdx.x;
    // idx = ((b*NA + a)*NV + v)*NU + u   (u fastest -> coalesced out write)
    const int u   = idx % NUg;
    int tmp       = idx / NUg;
    const int v   = tmp % NVg;
    tmp          /= NVg;
    const int a   = tmp % NAg;
    const int b   = tmp / NAg;

    // theta = a * (f32(2*pi) / 48)   [jax linspace f32 semantics]
    const float dtheta = 6.2831855f / 48.0f;   // compile-time f32 CR division
    const float theta  = (float)a * dtheta;
    // correctly-rounded f32 sin/cos via f64 (matches glibc CR cosf/sinf;
    // within <=1 ulp of any sane f32 libm)
    const float c = (float)cos((double)theta);
    const float s = (float)sin((double)theta);

    // source / detector pixel (x,y,z), ref op order, f32, no contraction
    const float srcx = 500.0f * c;
    const float srcy = 500.0f * s;
    const float uu = ((float)u - 47.5f) * 2.0f;   // exact
    const float vv = ((float)v - 47.5f) * 2.0f;   // exact
    const float pixx = (-500.0f * c) + uu * (-s); // det_c + u*u_ax ((+v*0) is a no-op)
    const float pixy = (-500.0f * s) + uu * c;
    const float pixz = vv;

    const float dx0 = pixx - srcx;
    const float dy0 = pixy - srcy;
    const float dz0 = pixz;                        // - 0
    const float nrm = sqrtf((dx0 * dx0 + dy0 * dy0) + dz0 * dz0); // ref reduce order
    const float dx = dx0 / nrm;                    // IEEE division
    const float dy = dy0 / nrm;
    const float dz = dz0 / nrm;

    // f32(2R/96), f32(DSO - R) folded from f64 exactly as Python computes them
    const float stepf = (float)1.7320508075688773;   // 2*R/96 in f64 -> f32
    const float t0f   = (float)416.8615612366939;    // 500 - R in f64 -> f32

    // ---- conservative AABB clip of sample index range (skip-only; the
    //      exact in-loop validity test is authoritative) ------------------
    const float LO = -47.51f, HI = 47.51f;
    float tlo = -1e30f, thi = 1e30f;
    {
        const float o3[3] = {srcx, srcy, 0.0f};
        const float d3[3] = {dx, dy, dz};
        bool empty = false;
        #pragma unroll
        for (int ax = 0; ax < 3; ++ax) {
            const float oo = o3[ax], dd = d3[ax];
            if (fabsf(dd) > 1e-8f) {
                const float inv = 1.0f / dd;
                const float ta = (LO - oo) * inv;
                const float tb = (HI - oo) * inv;
                tlo = fmaxf(tlo, fminf(ta, tb));
                thi = fminf(thi, fmaxf(ta, tb));
            } else if (oo < LO || oo > HI) {
                empty = true;
            }
        }
        if (empty) { tlo = 1.0f; thi = 0.0f; }
    }
    int k0, k1;
    if (thi >= tlo) {
        k0 = (int)floorf((tlo - t0f) / stepf) - 2;
        k1 = (int)ceilf((thi - t0f) / stepf) + 2;
        k0 = max(k0, 0);
        k1 = min(k1, NSg - 1);
    } else {
        k0 = 1; k1 = 0;  // empty
    }

    const float* __restrict__ volb = vol + (size_t)b * (NZg * NYg * NXg);

    float acc = 0.0f;
    for (int k = k0; k <= k1; ++k) {
        // ref: t = f32(DSO-R) + (k+0.5)*step ; pw = src + d*t ; i = pw + 47.5
        const float tk = t0f + ((float)k + 0.5f) * stepf;
        const float ix = (srcx + dx * tk) + 47.5f;
        const float iy = (srcy + dy * tk) + 47.5f;
        const float iz = (dz * tk) + 47.5f;        // src_z = 0
        if (ix >= 0.0f && ix <= 95.0f &&
            iy >= 0.0f && iy <= 95.0f &&
            iz >= 0.0f && iz <= 95.0f) {
            const int x0 = min((int)ix, NXg - 2);  // ix>=0 so trunc==floor
            const int y0 = min((int)iy, NYg - 2);
            const int z0 = min((int)iz, NZg - 2);
            const float fx = ix - (float)x0;
            const float fy = iy - (float)y0;
            const float fz = iz - (float)z0;
            const float* p = volb + ((z0 * NYg + y0) * NXg + x0);
            const float v000 = p[0];
            const float v001 = p[1];
            const float v010 = p[NXg];
            const float v011 = p[NXg + 1];
            const float v100 = p[NYg * NXg];
            const float v101 = p[NYg * NXg + 1];
            const float v110 = p[NYg * NXg + NXg];
            const float v111 = p[NYg * NXg + NXg + 1];
            const float c00 = v000 + fx * (v001 - v000);
            const float c01 = v010 + fx * (v011 - v010);
            const float c10 = v100 + fx * (v101 - v100);
            const float c11 = v110 + fx * (v111 - v110);
            const float c0  = c00 + fy * (c01 - c00);
            const float c1  = c10 + fy * (c11 - c10);
            acc += c0 + fz * (c1 - c0);
        }
    }
    out[idx] = acc * stepf;
}

extern "C" void kernel_launch(void* const* d_in, const int* in_sizes, int n_in,
                              void* d_out, int out_size, void* d_ws, size_t ws_size,
                              hipStream_t stream) {
    const float* vol = (const float*)d_in[0];
    float* out = (float*)d_out;
    const int total = NBg * NAg * NVg * NUg;  // 884736 == out_size
    coneproj_kernel<<<total / 256, 256, 0, stream>>>(vol, out);
}

// Round 3
// 319.504 us; speedup vs baseline: 1.0043x; 1.0043x over previous
//
#include <hip/hip_runtime.h>
#include <math.h>

// Cone-beam forward projection (TIGRE Ax analogue).
// Volume: [B=2, NZ=96, NY=96, NX=96] f32, ZYX layout (x fastest).
// Output: [B=2, A=48, NV=96, NU=96] f32.
// One thread per ray; NS=96 samples.
//
// CORRECTNESS-CRITICAL: reference integrand is DISCONTINUOUS at cube faces.
// Position path replicates the reference's f32 op sequence exactly:
// contract(off), per-sample src + d*t, IEEE sqrt+div, f64-rounded trig.
// R2 change: fuse the 8 trilinear taps into 4 dwordx2 gathers (x-pairs share
// a cacheline ~94%); values and sum order are bit-identical to R1.

#define NZg 96
#define NYg 96
#define NXg 96
#define NVg 96
#define NUg 96
#define NAg 48
#define NSg 96
#define NBg 2

// 8-byte vector load with only 4-byte alignment guarantee (gfx9+ handles it)
typedef float f2u __attribute__((ext_vector_type(2), aligned(4)));

__global__ __launch_bounds__(256) void coneproj_kernel(
    const float* __restrict__ vol, float* __restrict__ out) {
#pragma clang fp contract(off)
    const int idx = blockIdx.x * blockDim.x + threadIdx.x;
    // idx = ((b*NA + a)*NV + v)*NU + u   (u fastest -> coalesced out write)
    const int u   = idx % NUg;
    int tmp       = idx / NUg;
    const int v   = tmp % NVg;
    tmp          /= NVg;
    const int a   = tmp % NAg;
    const int b   = tmp / NAg;

    // theta = a * (f32(2*pi) / 48)   [jax linspace f32 semantics]
    const float dtheta = 6.2831855f / 48.0f;
    const float theta  = (float)a * dtheta;
    const float c = (float)cos((double)theta);
    const float s = (float)sin((double)theta);

    // source / detector pixel (x,y,z), ref op order, f32, no contraction
    const float srcx = 500.0f * c;
    const float srcy = 500.0f * s;
    const float uu = ((float)u - 47.5f) * 2.0f;
    const float vv = ((float)v - 47.5f) * 2.0f;
    const float pixx = (-500.0f * c) + uu * (-s);
    const float pixy = (-500.0f * s) + uu * c;
    const float pixz = vv;

    const float dx0 = pixx - srcx;
    const float dy0 = pixy - srcy;
    const float dz0 = pixz;
    const float nrm = sqrtf((dx0 * dx0 + dy0 * dy0) + dz0 * dz0);
    const float dx = dx0 / nrm;
    const float dy = dy0 / nrm;
    const float dz = dz0 / nrm;

    const float stepf = (float)1.7320508075688773;   // f32(2R/96)
    const float t0f   = (float)416.8615612366939;    // f32(DSO-R)

    // conservative AABB clip of sample range (skip-only; in-loop test is
    // authoritative)
    const float LO = -47.51f, HI = 47.51f;
    float tlo = -1e30f, thi = 1e30f;
    {
        const float o3[3] = {srcx, srcy, 0.0f};
        const float d3[3] = {dx, dy, dz};
        bool empty = false;
        #pragma unroll
        for (int ax = 0; ax < 3; ++ax) {
            const float oo = o3[ax], dd = d3[ax];
            if (fabsf(dd) > 1e-8f) {
                const float inv = 1.0f / dd;
                const float ta = (LO - oo) * inv;
                const float tb = (HI - oo) * inv;
                tlo = fmaxf(tlo, fminf(ta, tb));
                thi = fminf(thi, fmaxf(ta, tb));
            } else if (oo < LO || oo > HI) {
                empty = true;
            }
        }
        if (empty) { tlo = 1.0f; thi = 0.0f; }
    }
    int k0, k1;
    if (thi >= tlo) {
        k0 = (int)floorf((tlo - t0f) / stepf) - 2;
        k1 = (int)ceilf((thi - t0f) / stepf) + 2;
        k0 = max(k0, 0);
        k1 = min(k1, NSg - 1);
    } else {
        k0 = 1; k1 = 0;
    }

    const float* __restrict__ volb = vol + (size_t)b * (NZg * NYg * NXg);

    float acc = 0.0f;
    #pragma unroll 2
    for (int k = k0; k <= k1; ++k) {
        const float tk = t0f + ((float)k + 0.5f) * stepf;
        const float ix = (srcx + dx * tk) + 47.5f;
        const float iy = (srcy + dy * tk) + 47.5f;
        const float iz = (dz * tk) + 47.5f;
        if (ix >= 0.0f && ix <= 95.0f &&
            iy >= 0.0f && iy <= 95.0f &&
            iz >= 0.0f && iz <= 95.0f) {
            const int x0 = min((int)ix, NXg - 2);
            const int y0 = min((int)iy, NYg - 2);
            const int z0 = min((int)iz, NZg - 2);
            const float fx = ix - (float)x0;
            const float fy = iy - (float)y0;
            const float fz = iz - (float)z0;
            const float* p = volb + ((z0 * NYg + y0) * NXg + x0);
            // 4 x-pair gathers (v_00 = {v..0, v..1}) — same values as 8 scalar
            const f2u q00 = *(const f2u*)(p);
            const f2u q01 = *(const f2u*)(p + NXg);
            const f2u q10 = *(const f2u*)(p + NYg * NXg);
            const f2u q11 = *(const f2u*)(p + NYg * NXg + NXg);
            const float c00 = q00.x + fx * (q00.y - q00.x);
            const float c01 = q01.x + fx * (q01.y - q01.x);
            const float c10 = q10.x + fx * (q10.y - q10.x);
            const float c11 = q11.x + fx * (q11.y - q11.x);
            const float c0  = c00 + fy * (c01 - c00);
            const float c1  = c10 + fy * (c11 - c10);
            acc += c0 + fz * (c1 - c0);
        }
    }
    out[idx] = acc * stepf;
}

extern "C" void kernel_launch(void* const* d_in, const int* in_sizes, int n_in,
                              void* d_out, int out_size, void* d_ws, size_t ws_size,
                              hipStream_t stream) {
    const float* vol = (const float*)d_in[0];
    float* out = (float*)d_out;
    const int total = NBg * NAg * NVg * NUg;  // 884736 == out_size
    coneproj_kernel<<<total / 256, 256, 0, stream>>>(vol, out);
}